// Round 15
// baseline (86.114 us; speedup 1.0000x reference)
//
#include <hip/hip_runtime.h>

// ---------------------------------------------------------------------------
// SpeciesSpecificNetworkBranch — R15 = R11 (best, 63.7us) + by-species
// phase-B sessions to cut L2 weight traffic 6x.
//
// Theory: phase B reloaded 8KB of weight frags per TILE per wave from L2:
// 288KB/window -> ~1.1GB over the kernel ~ 18 TB/s of L2 reads + stream
// traffic ~ L2 ceiling. That is the shared resource that kept every R8-R14
// variant at the same speed with all pipes idle. Fix: tiles are species-
// sorted, so assign species->waves (ss = wav, wav+4) and load weights once
// per species session: ~48KB/window.
//
// Base structure (R11): 256-row window per block iteration; X prefetched into
// regs one window ahead; raw lgkm barriers (no vmcnt drain -> prefetch stays
// in flight); ballot-rank compaction into per-species 32-row tiles; phase B
// writes relu'd f32 results into a 32KB LDS out-buffer by natural local row
// (XOR swizzle); flush streams ob -> global fully coalesced.
//
// math: z1 = W1^T x + b1
//       z2 = W2f^T relu(z1) + Wsc^T x + bias2f     (W2f = diag(A1) W2)
//       out = relu(Wshf_s^T relu(z2) + bshf_s)     (0.92 pre-folded)
// C'[feature][sample] via mfma_f32_32x32x16_bf16; sample lane-local;
// relu + v_cvt_pk_bf16_f32 + permlane32_swap chains layers in registers.
// ---------------------------------------------------------------------------

#define EPSBN 1e-5f
#define TPB 256
#define WIN 256
#define NBLKMAX 768    // 3 blocks/CU (LDS ~52.8KB)

typedef __attribute__((ext_vector_type(8))) short bf16x8;
typedef __attribute__((ext_vector_type(16))) float f32x16;
typedef __attribute__((ext_vector_type(4))) unsigned u32x4;

union FU { unsigned u[4]; bf16x8 v; u32x4 q; };

static __device__ __forceinline__ unsigned pkbf(float lo, float hi) {
    unsigned r;
    asm("v_cvt_pk_bf16_f32 %0, %1, %2" : "=v"(r) : "v"(lo), "v"(hi));
    return r;
}

// raw barrier: LDS-visibility only (no vmcnt drain -> global prefetch stays
// in flight across it). All producers ordered by these barriers are LDS ops.
static __device__ __forceinline__ void ldsbar() {
    asm volatile("s_waitcnt lgkmcnt(0)" ::: "memory");
    __builtin_amdgcn_s_barrier();
}

// --- pre-pack: fold BN (and 0.92) into weights/biases, pack MFMA A-frags ---
// wfrag uints [s][m][c][64][4]  (m: 0=W1 1=Wsc 2=W2f 3=Wshf), 10240 words
// bconst floats [s][q][hi][16]  (q: 0=b1 1=bias2f 2=bshf), 480 floats
__global__ void k_pre(unsigned* __restrict__ wfrag, float* __restrict__ bconst,
                      const float* __restrict__ W1, const float* __restrict__ b1,
                      const float* __restrict__ g1, const float* __restrict__ be1,
                      const float* __restrict__ mu1, const float* __restrict__ va1,
                      const float* __restrict__ W2, const float* __restrict__ b2,
                      const float* __restrict__ g2, const float* __restrict__ be2,
                      const float* __restrict__ mu2, const float* __restrict__ va2,
                      const float* __restrict__ Wsc, const float* __restrict__ bsc,
                      const float* __restrict__ Wsh, const float* __restrict__ bsh) {
    if (blockIdx.x < 40) {
        const int i = blockIdx.x * 256 + threadIdx.x;   // wfrag word index
        const int p = i & 3, l = (i >> 2) & 63, c = (i >> 8) & 1;
        const int m = (i >> 9) & 3, s = i >> 11;
        const int ln = l & 31, hi = l >> 5;
        const int k0 = c * 16 + hi * 8 + 2 * p;
        float lo, hv;
        if (m == 0)      { lo = W1[s*1024 + k0*32 + ln];  hv = W1[s*1024 + (k0+1)*32 + ln]; }
        else if (m == 1) { lo = Wsc[s*1024 + k0*32 + ln]; hv = Wsc[s*1024 + (k0+1)*32 + ln]; }
        else if (m == 2) {
            float A0 = g1[s*32+k0]   * rsqrtf(va1[s*32+k0]   + EPSBN);
            float A1 = g1[s*32+k0+1] * rsqrtf(va1[s*32+k0+1] + EPSBN);
            lo = A0 * W2[s*1024 + k0*32 + ln]; hv = A1 * W2[s*1024 + (k0+1)*32 + ln];
        } else {
            float A0 = 0.92f * g2[s*32+k0]   * rsqrtf(va2[s*32+k0]   + EPSBN);
            float A1 = 0.92f * g2[s*32+k0+1] * rsqrtf(va2[s*32+k0+1] + EPSBN);
            lo = A0 * Wsh[k0*32 + ln]; hv = A1 * Wsh[(k0+1)*32 + ln];
        }
        wfrag[i] = pkbf(lo, hv);
    } else {
        for (int i = threadIdx.x; i < 480; i += 256) {
            const int reg = i & 15, hi = (i >> 4) & 1, t = i >> 5;
            const int q = t % 3, s = t / 3;
            const int r = (reg & 3) + 8 * (reg >> 2) + 4 * hi;
            float v;
            if (q == 0) v = b1[s*32 + r];
            else if (q == 1) {
                v = b2[s*32 + r] + bsc[s*32 + r];
                for (int k = 0; k < 32; ++k) {
                    float A = g1[s*32+k] * rsqrtf(va1[s*32+k] + EPSBN);
                    float C = be1[s*32+k] - mu1[s*32+k] * A;
                    v = fmaf(C, W2[s*1024 + k*32 + r], v);
                }
            } else {
                v = bsh[r];
                for (int k = 0; k < 32; ++k) {
                    float A = g2[s*32+k] * rsqrtf(va2[s*32+k] + EPSBN);
                    float C = be2[s*32+k] - mu2[s*32+k] * A;
                    v = fmaf(C, Wsh[k*32 + r], v);
                }
                v *= 0.92f;
            }
            bconst[i] = v;
        }
    }
}

// relu-only transition: C' acc -> next layer's B-frags (cvt_pk + permlane32).
static __device__ __forceinline__ void reluT(const f32x16& c, bf16x8& f0, bf16x8& f1) {
    unsigned p[8];
    #pragma unroll
    for (int i = 0; i < 8; ++i)
        p[i] = pkbf(fmaxf(c[2 * i], 0.f), fmaxf(c[2 * i + 1], 0.f));
    auto s0 = __builtin_amdgcn_permlane32_swap(p[0], p[2], false, false);
    auto s1 = __builtin_amdgcn_permlane32_swap(p[1], p[3], false, false);
    auto s2 = __builtin_amdgcn_permlane32_swap(p[4], p[6], false, false);
    auto s3 = __builtin_amdgcn_permlane32_swap(p[5], p[7], false, false);
    FU u0, u1;
    u0.u[0] = s0[0]; u0.u[1] = s1[0]; u0.u[2] = s0[1]; u0.u[3] = s1[1];
    u1.u[0] = s2[0]; u1.u[1] = s3[0]; u1.u[2] = s2[1]; u1.u[3] = s3[1];
    f0 = u0.v; f1 = u1.v;
}

__global__ __launch_bounds__(TPB, 3) void k_main(
    const float* __restrict__ X, const int* __restrict__ sid,
    const unsigned* __restrict__ wfrag, const float* __restrict__ bconst,
    float* __restrict__ out, int B) {
    __shared__ __align__(16) unsigned char xb[16384];  // bf16 [256 rows][4x16B], swizzled
    __shared__ __align__(16) float ob[8192];           // f32 out-stage [256 rows][32], swizzled
    __shared__ float clds[480];
    __shared__ int idxl[416];
    __shared__ int wq[4][5];

    const int tid = threadIdx.x;
    const int l   = tid & 63;
    const int ln  = l & 31;
    const int hi  = l >> 5;
    const int wav = tid >> 6;
    const unsigned long long ltmask = (1ull << l) - 1ull;

    for (int i = tid; i < 480; i += TPB) clds[i] = bconst[i];

    const int nwin = (B + WIN - 1) / WIN;
    const long fmaxo = (long)B * 32 - 8;

    // prefetched window data (registers)
    float4 pa[4], pb[4];
    int svp = -1;

    // prologue: load first window
    int w0 = blockIdx.x;
    if (w0 < nwin) {
        #pragma unroll
        for (int k = 0; k < 4; ++k) {
            long fo = (long)w0 * (WIN * 32) + k * 2048 + tid * 8;
            if (fo > fmaxo) fo = fmaxo;
            pa[k] = *(const float4*)(X + fo);
            pb[k] = *(const float4*)(X + fo + 4);
        }
        int row = w0 * WIN + tid;
        svp = (row < B) ? sid[row] : -1;
    }

    for (int w = w0; w < nwin; w += gridDim.x) {
        const int wbase = w * WIN;
        const int rows = min(WIN, B - wbase);

        // ---- stage: cvt prefetched regs -> bf16 LDS tile (swizzled slots)
        #pragma unroll
        for (int k = 0; k < 4; ++k) {
            FU u;
            u.u[0] = pkbf(pa[k].x, pa[k].y); u.u[1] = pkbf(pa[k].z, pa[k].w);
            u.u[2] = pkbf(pb[k].x, pb[k].y); u.u[3] = pkbf(pb[k].z, pb[k].w);
            const int row  = k * 64 + (tid >> 2);
            const int slot = (tid & 3) ^ (row & 3);
            *(u32x4*)(xb + row * 64 + slot * 16) = u.q;
        }

        // ---- ballots: per-wave counts + in-wave rank; sentinel idxl
        const int s = svp;
        int prank = 0;
        #pragma unroll
        for (int sp = 0; sp < 5; ++sp) {
            unsigned long long m = __ballot(s == sp);
            if (l == 0) wq[wav][sp] = (int)__popcll(m);
            if (s == sp) prank = (int)__popcll(m & ltmask);
        }
        for (int i = tid; i < 416; i += TPB) idxl[i] = -1;
        ldsbar();   // b1: xb, wq, sentinels visible

        // ---- all-thread scan: per-species tile bases
        int tb[6];
        {
            int t = 0;
            #pragma unroll
            for (int sp = 0; sp < 5; ++sp) {
                tb[sp] = t;
                int c = wq[0][sp] + wq[1][sp] + wq[2][sp] + wq[3][sp];
                t += (c + 31) >> 5;
            }
            tb[5] = t;
        }
        // ---- rank-write local row into species segment
        if (s >= 0) {
            int off = tb[s] * 32 + prank;
            for (int w2 = 0; w2 < wav; ++w2) off += wq[w2][s];
            idxl[off] = tid;
        }

        // ---- issue NEXT window's global loads (consumed next iteration; no
        //      vmcnt drain at the raw barriers -> latency hides under phase B)
        const int wn = w + gridDim.x;
        if (wn < nwin) {
            #pragma unroll
            for (int k = 0; k < 4; ++k) {
                long fo = (long)wn * (WIN * 32) + k * 2048 + tid * 8;
                if (fo > fmaxo) fo = fmaxo;
                pa[k] = *(const float4*)(X + fo);
                pb[k] = *(const float4*)(X + fo + 4);
            }
            int row = wn * WIN + tid;
            svp = (row < B) ? sid[row] : -1;
        }
        ldsbar();   // b2: idxl visible

        // ---- phase B: BY-SPECIES SESSIONS. Wave wav handles species
        //      ss = wav (and wav+4); weights loaded ONCE per session ->
        //      L2 weight traffic /6 (was the shared bottleneck).
        for (int ss = wav; ss < 5; ss += 4) {
            const int t0 = tb[ss], t1 = tb[ss + 1];
            if (t0 >= t1) continue;

            const unsigned* wp = wfrag + ss * 2048;   // coalesced, L2-hot
            FU w00, w01, w10, w11, w20, w21, w30, w31;
            w00.q = *(const u32x4*)(wp + (0 * 64 + l) * 4);
            w01.q = *(const u32x4*)(wp + (1 * 64 + l) * 4);
            w10.q = *(const u32x4*)(wp + (2 * 64 + l) * 4);
            w11.q = *(const u32x4*)(wp + (3 * 64 + l) * 4);
            w20.q = *(const u32x4*)(wp + (4 * 64 + l) * 4);
            w21.q = *(const u32x4*)(wp + (5 * 64 + l) * 4);
            w30.q = *(const u32x4*)(wp + (6 * 64 + l) * 4);
            w31.q = *(const u32x4*)(wp + (7 * 64 + l) * 4);
            const float* cp = clds + ss * 96;

            for (int t = t0; t < t1; ++t) {
                const int lid = idxl[t * 32 + ln];
                const int r = lid < 0 ? 0 : lid;

                f32x16 a1 = *(const f32x16*)(cp + hi * 16);
                f32x16 a2 = *(const f32x16*)(cp + 32 + hi * 16);

                const int rs = r & 3;
                const bf16x8 b0 = *(const bf16x8*)(xb + r * 64 + ((hi ^ rs) << 4));
                const bf16x8 b1 = *(const bf16x8*)(xb + r * 64 + (((2 + hi) ^ rs) << 4));

                a1 = __builtin_amdgcn_mfma_f32_32x32x16_bf16(w00.v, b0, a1, 0, 0, 0);
                a2 = __builtin_amdgcn_mfma_f32_32x32x16_bf16(w10.v, b0, a2, 0, 0, 0);
                a1 = __builtin_amdgcn_mfma_f32_32x32x16_bf16(w01.v, b1, a1, 0, 0, 0);
                a2 = __builtin_amdgcn_mfma_f32_32x32x16_bf16(w11.v, b1, a2, 0, 0, 0);

                bf16x8 h0, h1;
                reluT(a1, h0, h1);
                a2 = __builtin_amdgcn_mfma_f32_32x32x16_bf16(w20.v, h0, a2, 0, 0, 0);
                a2 = __builtin_amdgcn_mfma_f32_32x32x16_bf16(w21.v, h1, a2, 0, 0, 0);

                bf16x8 g0, g1;
                reluT(a2, g0, g1);
                f32x16 a3 = *(const f32x16*)(cp + 64 + hi * 16);
                a3 = __builtin_amdgcn_mfma_f32_32x32x16_bf16(w30.v, g0, a3, 0, 0, 0);
                a3 = __builtin_amdgcn_mfma_f32_32x32x16_bf16(w31.v, g1, a3, 0, 0, 0);

                if (lid >= 0) {
                    // write relu'd result into LDS out-stage at natural row lid,
                    // piece (hi,q) -> float offset (hi*4+q*8) ^ ((lid&7)<<2)
                    #pragma unroll
                    for (int q = 0; q < 4; ++q) {
                        float4 v;
                        v.x = fmaxf(a3[4 * q + 0], 0.f);
                        v.y = fmaxf(a3[4 * q + 1], 0.f);
                        v.z = fmaxf(a3[4 * q + 2], 0.f);
                        v.w = fmaxf(a3[4 * q + 3], 0.f);
                        const int fs = (hi * 4 + q * 8) ^ ((lid & 7) << 2);
                        *(float4*)(ob + lid * 32 + fs) = v;
                    }
                }
            }
        }
        ldsbar();   // b3: ob visible

        // ---- flush: LDS out-stage -> global, fully coalesced 16B pieces
        #pragma unroll
        for (int k = 0; k < 8; ++k) {
            const int p = k * TPB + tid;
            const int row = p >> 3, sl = p & 7;
            if (row < rows) {
                const int fs = (sl * 4) ^ ((row & 7) << 2);
                float4 v = *(const float4*)(ob + row * 32 + fs);
                *(float4*)(out + (long)(wbase + row) * 32 + sl * 4) = v;
            }
        }
    }
}

extern "C" void kernel_launch(void* const* d_in, const int* in_sizes, int n_in,
                              void* d_out, int out_size, void* d_ws, size_t ws_size,
                              hipStream_t stream) {
    const float* X   = (const float*)d_in[0];
    const int*   sid = (const int*)d_in[1];
    const float* W1  = (const float*)d_in[2];
    const float* b1  = (const float*)d_in[3];
    const float* g1  = (const float*)d_in[4];
    const float* be1 = (const float*)d_in[5];
    const float* mu1 = (const float*)d_in[6];
    const float* va1 = (const float*)d_in[7];
    const float* W2  = (const float*)d_in[8];
    const float* b2  = (const float*)d_in[9];
    const float* g2  = (const float*)d_in[10];
    const float* be2 = (const float*)d_in[11];
    const float* mu2 = (const float*)d_in[12];
    const float* va2 = (const float*)d_in[13];
    const float* Wsc = (const float*)d_in[14];
    const float* bsc = (const float*)d_in[15];
    const float* Wsh = (const float*)d_in[16];
    const float* bsh = (const float*)d_in[17];
    float* out = (float*)d_out;
    const int B = in_sizes[1];

    unsigned* wfrag = (unsigned*)d_ws;          // 10240 u32
    float* bconst   = (float*)(wfrag + 10240);  // 480 f32

    k_pre<<<41, 256, 0, stream>>>(wfrag, bconst,
                                  W1, b1, g1, be1, mu1, va1,
                                  W2, b2, g2, be2, mu2, va2,
                                  Wsc, bsc, Wsh, bsh);

    const int nwin = (B + WIN - 1) / WIN;
    const int nblocks = min(NBLKMAX, nwin);
    k_main<<<nblocks, TPB, 0, stream>>>(X, sid, wfrag, bconst, out, B);
}

// Round 16
// 81.366 us; speedup vs baseline: 1.0584x; 1.0584x over previous
//
#include <hip/hip_runtime.h>

// ---------------------------------------------------------------------------
// SpeciesSpecificNetworkBranch — R16: wave-autonomous, barrier-free.
//
// R8-R15 invariant: ~12us per 256-row window per block with all pipes idle —
// the block's 3-4 barriers/window lockstep its waves; during waits no memory
// ops issue, and only 3 blocks/CU stream independently.
// R16: each WAVE owns private 128-row windows. Compaction is wave-synchronous
// ballot work (counts/ranks in regs, private idxl slice) -> ZERO barriers in
// the loop (one ldsbar at start for the shared const table). Every wave keeps
// its next window's 16 loads in flight at all times; stalled waves block
// nobody. Final layer uses swapped MFMA operands (R13-verified) so stores are
// 128B-contiguous rows -> no LDS out-staging.
// launch_bounds(256,2): VGPR cap 256 >> ~190 live — spill impossible
// (R5/R12/R15 failure mode).
//
// math: z1 = W1^T x + b1
//       z2 = W2f^T relu(z1) + Wsc^T x + bias2f     (W2f = diag(A1) W2)
//       out = relu(Wshf_s^T relu(z2) + bshf_s)     (0.92 pre-folded)
// Layers 1-2: C'[feature][sample] = mfma(W, act): sample lane-local for
// in-register chaining (relu + cvt_pk_bf16 + permlane32_swap).
// Layer 3: D[sample][feature] = mfma(act, W): feature lane-local -> coalesced.
// ---------------------------------------------------------------------------

#define EPSBN 1e-5f
#define TPB 256
#define WWIN 128        // rows per WAVE-window
#define NBLK 512        // 2 blocks/CU resident (launch_bounds(256,2))

typedef __attribute__((ext_vector_type(8))) short bf16x8;
typedef __attribute__((ext_vector_type(16))) float f32x16;
typedef __attribute__((ext_vector_type(4))) unsigned u32x4;

union FU { unsigned u[4]; bf16x8 v; u32x4 q; };

static __device__ __forceinline__ unsigned pkbf(float lo, float hi) {
    unsigned r;
    asm("v_cvt_pk_bf16_f32 %0, %1, %2" : "=v"(r) : "v"(lo), "v"(hi));
    return r;
}

static __device__ __forceinline__ void ldsbar() {
    asm volatile("s_waitcnt lgkmcnt(0)" ::: "memory");
    __builtin_amdgcn_s_barrier();
}

// --- pre-pack: fold BN (and 0.92) into weights/biases, pack MFMA A-frags ---
// wfrag uints [s][m][c][64][4]  (m: 0=W1 1=Wsc 2=W2f 3=Wshf), 10240 words
// bconst floats [s][q][hi][16] (q: 0=b1 1=bias2f 2=bshf), 480 floats
//        + plain bshf table [s][32] at offset 480 (160 floats)
__global__ void k_pre(unsigned* __restrict__ wfrag, float* __restrict__ bconst,
                      const float* __restrict__ W1, const float* __restrict__ b1,
                      const float* __restrict__ g1, const float* __restrict__ be1,
                      const float* __restrict__ mu1, const float* __restrict__ va1,
                      const float* __restrict__ W2, const float* __restrict__ b2,
                      const float* __restrict__ g2, const float* __restrict__ be2,
                      const float* __restrict__ mu2, const float* __restrict__ va2,
                      const float* __restrict__ Wsc, const float* __restrict__ bsc,
                      const float* __restrict__ Wsh, const float* __restrict__ bsh) {
    if (blockIdx.x < 40) {
        const int i = blockIdx.x * 256 + threadIdx.x;   // wfrag word index
        const int p = i & 3, l = (i >> 2) & 63, c = (i >> 8) & 1;
        const int m = (i >> 9) & 3, s = i >> 11;
        const int ln = l & 31, hi = l >> 5;
        const int k0 = c * 16 + hi * 8 + 2 * p;
        float lo, hv;
        if (m == 0)      { lo = W1[s*1024 + k0*32 + ln];  hv = W1[s*1024 + (k0+1)*32 + ln]; }
        else if (m == 1) { lo = Wsc[s*1024 + k0*32 + ln]; hv = Wsc[s*1024 + (k0+1)*32 + ln]; }
        else if (m == 2) {
            float A0 = g1[s*32+k0]   * rsqrtf(va1[s*32+k0]   + EPSBN);
            float A1 = g1[s*32+k0+1] * rsqrtf(va1[s*32+k0+1] + EPSBN);
            lo = A0 * W2[s*1024 + k0*32 + ln]; hv = A1 * W2[s*1024 + (k0+1)*32 + ln];
        } else {
            float A0 = 0.92f * g2[s*32+k0]   * rsqrtf(va2[s*32+k0]   + EPSBN);
            float A1 = 0.92f * g2[s*32+k0+1] * rsqrtf(va2[s*32+k0+1] + EPSBN);
            lo = A0 * Wsh[k0*32 + ln]; hv = A1 * Wsh[(k0+1)*32 + ln];
        }
        wfrag[i] = pkbf(lo, hv);
    } else {
        for (int i = threadIdx.x; i < 480; i += 256) {
            const int reg = i & 15, hi = (i >> 4) & 1, t = i >> 5;
            const int q = t % 3, s = t / 3;
            const int r = (reg & 3) + 8 * (reg >> 2) + 4 * hi;
            float v;
            if (q == 0) v = b1[s*32 + r];
            else if (q == 1) {
                v = b2[s*32 + r] + bsc[s*32 + r];
                for (int k = 0; k < 32; ++k) {
                    float A = g1[s*32+k] * rsqrtf(va1[s*32+k] + EPSBN);
                    float C = be1[s*32+k] - mu1[s*32+k] * A;
                    v = fmaf(C, W2[s*1024 + k*32 + r], v);
                }
            } else {
                v = bsh[r];
                for (int k = 0; k < 32; ++k) {
                    float A = g2[s*32+k] * rsqrtf(va2[s*32+k] + EPSBN);
                    float C = be2[s*32+k] - mu2[s*32+k] * A;
                    v = fmaf(C, Wsh[k*32 + r], v);
                }
                v *= 0.92f;
                bconst[480 + s * 32 + r] = v;   // plain [s][feature] copy
            }
            bconst[i] = v;
        }
    }
}

// relu-only transition: C' acc -> next layer's B-frags (cvt_pk + permlane32).
static __device__ __forceinline__ void reluT(const f32x16& c, bf16x8& f0, bf16x8& f1) {
    unsigned p[8];
    #pragma unroll
    for (int i = 0; i < 8; ++i)
        p[i] = pkbf(fmaxf(c[2 * i], 0.f), fmaxf(c[2 * i + 1], 0.f));
    auto s0 = __builtin_amdgcn_permlane32_swap(p[0], p[2], false, false);
    auto s1 = __builtin_amdgcn_permlane32_swap(p[1], p[3], false, false);
    auto s2 = __builtin_amdgcn_permlane32_swap(p[4], p[6], false, false);
    auto s3 = __builtin_amdgcn_permlane32_swap(p[5], p[7], false, false);
    FU u0, u1;
    u0.u[0] = s0[0]; u0.u[1] = s1[0]; u0.u[2] = s0[1]; u0.u[3] = s1[1];
    u1.u[0] = s2[0]; u1.u[1] = s3[0]; u1.u[2] = s2[1]; u1.u[3] = s3[1];
    f0 = u0.v; f1 = u1.v;
}

__global__ __launch_bounds__(TPB, 2) void k_main(
    const float* __restrict__ X, const int* __restrict__ sid,
    const unsigned* __restrict__ wfrag, const float* __restrict__ bconst,
    float* __restrict__ out, int B) {
    // per-wave slices: xb 8KB (bf16 [128 rows][4x16B slots, swizzled]),
    // idxl 256 ints. clds is block-shared, written once + single ldsbar.
    __shared__ __align__(16) unsigned char xb[4 * 8192];
    __shared__ int idxl[4 * 256];
    __shared__ float clds[640];

    const int tid = threadIdx.x;
    const int l   = tid & 63;
    const int ln  = l & 31;
    const int hi  = l >> 5;
    const int wav = tid >> 6;
    const unsigned long long ltmask = (1ull << l) - 1ull;

    unsigned char* xbw = xb + wav * 8192;
    int* idxw = idxl + wav * 256;

    for (int i = tid; i < 640; i += TPB) clds[i] = bconst[i];
    ldsbar();   // the ONLY barrier: clds visible to all waves

    const int nwin = (B + WWIN - 1) / WWIN;
    const int gw   = blockIdx.x * 4 + wav;       // global wave id
    const int nw   = gridDim.x * 4;
    const long fmaxo = (long)B * 32 - 8;

    // prefetch buffers: one full 128-row window (16 float4 = 64 VGPR in flight)
    float4 pa[8], pb[8];
    int svp0 = -1, svp1 = -1;

    int w0 = gw;
    if (w0 < nwin) {
        #pragma unroll
        for (int k = 0; k < 8; ++k) {
            long fo = (long)w0 * (WWIN * 32) + k * 512 + l * 8;
            if (fo > fmaxo) fo = fmaxo;
            pa[k] = *(const float4*)(X + fo);
            pb[k] = *(const float4*)(X + fo + 4);
        }
        int r0 = w0 * WWIN + l, r1 = r0 + 64;
        svp0 = (r0 < B) ? sid[min(r0, B - 1)] : -1;
        svp1 = (r1 < B) ? sid[min(r1, B - 1)] : -1;
    }

    for (int w = w0; w < nwin; w += nw) {
        const int wbase = w * WWIN;

        // ---- stage: cvt prefetched regs -> bf16 LDS (swizzled 16B slots)
        #pragma unroll
        for (int k = 0; k < 8; ++k) {
            FU u;
            u.u[0] = pkbf(pa[k].x, pa[k].y); u.u[1] = pkbf(pa[k].z, pa[k].w);
            u.u[2] = pkbf(pb[k].x, pb[k].y); u.u[3] = pkbf(pb[k].z, pb[k].w);
            const int row  = k * 16 + (l >> 2);
            const int slot = (l & 3) ^ (row & 3);
            *(u32x4*)(xbw + row * 64 + slot * 16) = u.q;
        }

        // ---- wave-local ballots: counts + ranks for 2 iters of 64 rows
        const int sv0 = svp0, sv1 = svp1;
        int c0[5], c1[5], rk0 = 0, rk1 = 0;
        #pragma unroll
        for (int sp = 0; sp < 5; ++sp) {
            unsigned long long m0 = __ballot(sv0 == sp);
            unsigned long long m1 = __ballot(sv1 == sp);
            c0[sp] = (int)__popcll(m0);
            c1[sp] = (int)__popcll(m1);
            if (sv0 == sp) rk0 = (int)__popcll(m0 & ltmask);
            if (sv1 == sp) rk1 = (int)__popcll(m1 & ltmask);
        }

        // ---- register scan: tile bases
        int tb[6];
        {
            int t = 0;
            #pragma unroll
            for (int sp = 0; sp < 5; ++sp) {
                tb[sp] = t;
                t += (c0[sp] + c1[sp] + 31) >> 5;
            }
            tb[5] = t;
        }
        const int ntl = tb[5];

        // ---- sentinel-fill used idxl range, then rank-write local rows
        for (int i = l; i < ntl * 32; i += 64) idxw[i] = -1;
        if (sv0 >= 0) idxw[tb[sv0] * 32 + rk0] = l;
        if (sv1 >= 0) idxw[tb[sv1] * 32 + c0[sv1] + rk1] = 64 + l;

        // ---- issue NEXT window's loads (pa/pb free after stage; these stay
        //      in flight through phase B — no barriers to drain them)
        const int wn = w + nw;
        if (wn < nwin) {
            #pragma unroll
            for (int k = 0; k < 8; ++k) {
                long fo = (long)wn * (WWIN * 32) + k * 512 + l * 8;
                if (fo > fmaxo) fo = fmaxo;
                pa[k] = *(const float4*)(X + fo);
                pb[k] = *(const float4*)(X + fo + 4);
            }
            int r0 = wn * WWIN + l, r1 = r0 + 64;
            svp0 = (r0 < B) ? sid[min(r0, B - 1)] : -1;
            svp1 = (r1 < B) ? sid[min(r1, B - 1)] : -1;
        }

        // ---- phase B: this wave's tiles (species-sorted; weights reload only
        //      on species change, <=5 per window)
        int csp = -1;
        FU w00, w01, w10, w11, w20, w21, w30, w31;
        for (int t = 0; t < ntl; ++t) {
            int nsp = 0;
            #pragma unroll
            for (int k = 1; k < 5; ++k) nsp += (t >= tb[k]) ? 1 : 0;
            nsp = __builtin_amdgcn_readfirstlane(nsp);
            if (nsp != csp) {
                csp = nsp;
                const unsigned* wp = wfrag + csp * 2048;
                w00.q = *(const u32x4*)(wp + (0 * 64 + l) * 4);
                w01.q = *(const u32x4*)(wp + (1 * 64 + l) * 4);
                w10.q = *(const u32x4*)(wp + (2 * 64 + l) * 4);
                w11.q = *(const u32x4*)(wp + (3 * 64 + l) * 4);
                w20.q = *(const u32x4*)(wp + (4 * 64 + l) * 4);
                w21.q = *(const u32x4*)(wp + (5 * 64 + l) * 4);
                w30.q = *(const u32x4*)(wp + (6 * 64 + l) * 4);
                w31.q = *(const u32x4*)(wp + (7 * 64 + l) * 4);
            }
            const int lid = idxw[t * 32 + ln];
            const int r = lid < 0 ? 0 : lid;

            const float* cp = clds + csp * 96;
            f32x16 a1 = *(const f32x16*)(cp + hi * 16);
            f32x16 a2 = *(const f32x16*)(cp + 32 + hi * 16);

            const int rs = r & 3;
            const bf16x8 b0 = *(const bf16x8*)(xbw + r * 64 + ((hi ^ rs) << 4));
            const bf16x8 b1 = *(const bf16x8*)(xbw + r * 64 + (((2 + hi) ^ rs) << 4));

            a1 = __builtin_amdgcn_mfma_f32_32x32x16_bf16(w00.v, b0, a1, 0, 0, 0);
            a2 = __builtin_amdgcn_mfma_f32_32x32x16_bf16(w10.v, b0, a2, 0, 0, 0);
            a1 = __builtin_amdgcn_mfma_f32_32x32x16_bf16(w01.v, b1, a1, 0, 0, 0);
            a2 = __builtin_amdgcn_mfma_f32_32x32x16_bf16(w11.v, b1, a2, 0, 0, 0);

            bf16x8 h0, h1;
            reluT(a1, h0, h1);
            a2 = __builtin_amdgcn_mfma_f32_32x32x16_bf16(w20.v, h0, a2, 0, 0, 0);
            a2 = __builtin_amdgcn_mfma_f32_32x32x16_bf16(w21.v, h1, a2, 0, 0, 0);

            bf16x8 g0, g1;
            reluT(a2, g0, g1);

            // final layer TRANSPOSED: lane = feature, reg = sample -> each
            // reg's store is a 128B-contiguous row (R13-verified layout)
            const float bsh_n = clds[480 + csp * 32 + ln];
            f32x16 a3;
            #pragma unroll
            for (int rr = 0; rr < 16; ++rr) a3[rr] = bsh_n;
            a3 = __builtin_amdgcn_mfma_f32_32x32x16_bf16(g0, w30.v, a3, 0, 0, 0);
            a3 = __builtin_amdgcn_mfma_f32_32x32x16_bf16(g1, w31.v, a3, 0, 0, 0);

            #pragma unroll
            for (int reg = 0; reg < 16; ++reg) {
                const int si = (reg & 3) + 8 * (reg >> 2) + 4 * hi;  // sample in tile
                const int lid2 = idxw[t * 32 + si];
                if (lid2 >= 0)
                    out[(long)(wbase + lid2) * 32 + ln] = fmaxf(a3[reg], 0.f);
            }
        }
    }
}

extern "C" void kernel_launch(void* const* d_in, const int* in_sizes, int n_in,
                              void* d_out, int out_size, void* d_ws, size_t ws_size,
                              hipStream_t stream) {
    const float* X   = (const float*)d_in[0];
    const int*   sid = (const int*)d_in[1];
    const float* W1  = (const float*)d_in[2];
    const float* b1  = (const float*)d_in[3];
    const float* g1  = (const float*)d_in[4];
    const float* be1 = (const float*)d_in[5];
    const float* mu1 = (const float*)d_in[6];
    const float* va1 = (const float*)d_in[7];
    const float* W2  = (const float*)d_in[8];
    const float* b2  = (const float*)d_in[9];
    const float* g2  = (const float*)d_in[10];
    const float* be2 = (const float*)d_in[11];
    const float* mu2 = (const float*)d_in[12];
    const float* va2 = (const float*)d_in[13];
    const float* Wsc = (const float*)d_in[14];
    const float* bsc = (const float*)d_in[15];
    const float* Wsh = (const float*)d_in[16];
    const float* bsh = (const float*)d_in[17];
    float* out = (float*)d_out;
    const int B = in_sizes[1];

    unsigned* wfrag = (unsigned*)d_ws;          // 10240 u32
    float* bconst   = (float*)(wfrag + 10240);  // 640 f32

    k_pre<<<41, 256, 0, stream>>>(wfrag, bconst,
                                  W1, b1, g1, be1, mu1, va1,
                                  W2, b2, g2, be2, mu2, va2,
                                  Wsc, bsc, Wsh, bsh);

    const int nwin = (B + WWIN - 1) / WWIN;
    const int nblocks = min(NBLK, (nwin + 3) / 4);
    k_main<<<nblocks, TPB, 0, stream>>>(X, sid, wfrag, bconst, out, B);
}

// Round 17
// 72.437 us; speedup vs baseline: 1.1888x; 1.1233x over previous
//
#include <hip/hip_runtime.h>

// ---------------------------------------------------------------------------
// SpeciesSpecificNetworkBranch — R17 = R11 (best, 63.7us) with phase B made
// vmcnt-free: weights live in LDS, computed per-block in the prologue.
//
// Mechanism (from R16's elimination): vmcnt is ORDERED. R11 issued the next
// window's X prefetch, then phase B loaded weights from global per tile;
// consuming the (newer) weight loads forces draining the (older) prefetch ->
// phase B's first tile serialized against the whole window prefetch (~900cy)
// per window per wave. R17: the BN-folded frag-packed weight table (40KB) is
// computed into LDS once per block (k_pre deleted -> one less launch; the
// prologue compute also hides the first prefetch). Phase B = LDS + MFMA only;
// the sole vmcnt consumer is the stage phase (prefetch had all of phase B in
// flight). ob packed bf16 (16KB) to fit 77.4KB LDS -> 2 blocks/CU.
// launch_bounds(256,2): VGPR cap 256 — spill impossible (R5/R12/R15 mode).
//
// math: z1 = W1^T x + b1
//       z2 = W2f^T relu(z1) + Wsc^T x + bias2f     (W2f = diag(A1) W2)
//       out = relu(Wshf_s^T relu(z2) + bshf_s)     (0.92 pre-folded)
// C'[feature][sample] via mfma_f32_32x32x16_bf16; sample lane-local;
// relu + v_cvt_pk_bf16_f32 + permlane32_swap chains layers in registers.
// ---------------------------------------------------------------------------

#define EPSBN 1e-5f
#define TPB 256
#define WIN 256
#define NBLK 512    // 2 blocks/CU (LDS 77.4KB)

typedef __attribute__((ext_vector_type(8))) short bf16x8;
typedef __attribute__((ext_vector_type(16))) float f32x16;
typedef __attribute__((ext_vector_type(4))) unsigned u32x4;
typedef __attribute__((ext_vector_type(2))) unsigned u32x2;

union FU { unsigned u[4]; bf16x8 v; u32x4 q; };

static __device__ __forceinline__ unsigned pkbf(float lo, float hi) {
    unsigned r;
    asm("v_cvt_pk_bf16_f32 %0, %1, %2" : "=v"(r) : "v"(lo), "v"(hi));
    return r;
}

// raw barrier: LDS-visibility only (no vmcnt drain -> global prefetch stays
// in flight across it). All producers ordered by these barriers are LDS ops.
static __device__ __forceinline__ void ldsbar() {
    asm volatile("s_waitcnt lgkmcnt(0)" ::: "memory");
    __builtin_amdgcn_s_barrier();
}

// relu-only transition: C' acc -> next layer's B-frags (cvt_pk + permlane32).
static __device__ __forceinline__ void reluT(const f32x16& c, bf16x8& f0, bf16x8& f1) {
    unsigned p[8];
    #pragma unroll
    for (int i = 0; i < 8; ++i)
        p[i] = pkbf(fmaxf(c[2 * i], 0.f), fmaxf(c[2 * i + 1], 0.f));
    auto s0 = __builtin_amdgcn_permlane32_swap(p[0], p[2], false, false);
    auto s1 = __builtin_amdgcn_permlane32_swap(p[1], p[3], false, false);
    auto s2 = __builtin_amdgcn_permlane32_swap(p[4], p[6], false, false);
    auto s3 = __builtin_amdgcn_permlane32_swap(p[5], p[7], false, false);
    FU u0, u1;
    u0.u[0] = s0[0]; u0.u[1] = s1[0]; u0.u[2] = s0[1]; u0.u[3] = s1[1];
    u1.u[0] = s2[0]; u1.u[1] = s3[0]; u1.u[2] = s2[1]; u1.u[3] = s3[1];
    f0 = u0.v; f1 = u1.v;
}

__global__ __launch_bounds__(TPB, 2) void k_main(
    const float* __restrict__ X, const int* __restrict__ sid,
    const float* __restrict__ W1, const float* __restrict__ b1,
    const float* __restrict__ g1, const float* __restrict__ be1,
    const float* __restrict__ mu1, const float* __restrict__ va1,
    const float* __restrict__ W2, const float* __restrict__ b2,
    const float* __restrict__ g2, const float* __restrict__ be2,
    const float* __restrict__ mu2, const float* __restrict__ va2,
    const float* __restrict__ Wsc, const float* __restrict__ bsc,
    const float* __restrict__ Wsh, const float* __restrict__ bsh,
    float* __restrict__ out, int B) {
    __shared__ __align__(16) unsigned wlds[10240];     // frag table [s][m][c][64][4]
    __shared__ __align__(16) unsigned char xb[16384];  // bf16 [256 rows][4x16B], swizzled
    __shared__ __align__(16) unsigned obh[4096];       // bf16 out-stage [256 rows][16 u32], swz
    __shared__ float clds[480];                        // [s][q][hi][16]
    __shared__ int idxl[416];
    __shared__ int wq[4][5];

    const int tid = threadIdx.x;
    const int l   = tid & 63;
    const int ln  = l & 31;
    const int hi  = l >> 5;
    const int wav = tid >> 6;
    const unsigned long long ltmask = (1ull << l) - 1ull;

    const int nwin = (B + WIN - 1) / WIN;
    const long fmaxo = (long)B * 32 - 8;

    // ---- issue first window's prefetch FIRST (hidden under prologue compute)
    float4 pa[4], pb[4];
    int svp = -1;
    const int w0 = blockIdx.x;
    if (w0 < nwin) {
        #pragma unroll
        for (int k = 0; k < 4; ++k) {
            long fo = (long)w0 * (WIN * 32) + k * 2048 + tid * 8;
            if (fo > fmaxo) fo = fmaxo;
            pa[k] = *(const float4*)(X + fo);
            pb[k] = *(const float4*)(X + fo + 4);
        }
        const int row = w0 * WIN + tid;
        svp = (row < B) ? sid[row] : -1;
    }

    // ---- prologue: compute folded weight frags + consts into LDS (per block)
    for (int i = tid; i < 10240; i += TPB) {
        const int p = i & 3, L = (i >> 2) & 63, c = (i >> 8) & 1;
        const int m = (i >> 9) & 3, s = i >> 11;
        const int LN = L & 31, HI = L >> 5;
        const int k0 = c * 16 + HI * 8 + 2 * p;
        float lo, hv;
        if (m == 0)      { lo = W1[s*1024 + k0*32 + LN];  hv = W1[s*1024 + (k0+1)*32 + LN]; }
        else if (m == 1) { lo = Wsc[s*1024 + k0*32 + LN]; hv = Wsc[s*1024 + (k0+1)*32 + LN]; }
        else if (m == 2) {
            float A0 = g1[s*32+k0]   * rsqrtf(va1[s*32+k0]   + EPSBN);
            float A1 = g1[s*32+k0+1] * rsqrtf(va1[s*32+k0+1] + EPSBN);
            lo = A0 * W2[s*1024 + k0*32 + LN]; hv = A1 * W2[s*1024 + (k0+1)*32 + LN];
        } else {
            float A0 = 0.92f * g2[s*32+k0]   * rsqrtf(va2[s*32+k0]   + EPSBN);
            float A1 = 0.92f * g2[s*32+k0+1] * rsqrtf(va2[s*32+k0+1] + EPSBN);
            lo = A0 * Wsh[k0*32 + LN]; hv = A1 * Wsh[(k0+1)*32 + LN];
        }
        wlds[i] = pkbf(lo, hv);
    }
    for (int i = tid; i < 480; i += TPB) {
        const int reg = i & 15, HI = (i >> 4) & 1, t = i >> 5;
        const int q = t % 3, s = t / 3;
        const int r = (reg & 3) + 8 * (reg >> 2) + 4 * HI;
        float v;
        if (q == 0) v = b1[s*32 + r];
        else if (q == 1) {
            v = b2[s*32 + r] + bsc[s*32 + r];
            for (int k = 0; k < 32; ++k) {
                float A = g1[s*32+k] * rsqrtf(va1[s*32+k] + EPSBN);
                float C = be1[s*32+k] - mu1[s*32+k] * A;
                v = fmaf(C, W2[s*1024 + k*32 + r], v);
            }
        } else {
            v = bsh[r];
            for (int k = 0; k < 32; ++k) {
                float A = g2[s*32+k] * rsqrtf(va2[s*32+k] + EPSBN);
                float C = be2[s*32+k] - mu2[s*32+k] * A;
                v = fmaf(C, Wsh[k*32 + r], v);
            }
            v *= 0.92f;
        }
        clds[i] = v;
    }
    // wlds/clds become visible via b1+b2 of the first loop iteration.

    for (int w = w0; w < nwin; w += gridDim.x) {
        const int wbase = w * WIN;
        const int rows = min(WIN, B - wbase);

        // ---- stage: cvt prefetched regs -> bf16 LDS tile (swizzled slots)
        #pragma unroll
        for (int k = 0; k < 4; ++k) {
            FU u;
            u.u[0] = pkbf(pa[k].x, pa[k].y); u.u[1] = pkbf(pa[k].z, pa[k].w);
            u.u[2] = pkbf(pb[k].x, pb[k].y); u.u[3] = pkbf(pb[k].z, pb[k].w);
            const int row  = k * 64 + (tid >> 2);
            const int slot = (tid & 3) ^ (row & 3);
            *(u32x4*)(xb + row * 64 + slot * 16) = u.q;
        }

        // ---- ballots: per-wave counts + in-wave rank; sentinel idxl
        const int s = svp;
        int prank = 0;
        #pragma unroll
        for (int sp = 0; sp < 5; ++sp) {
            unsigned long long m = __ballot(s == sp);
            if (l == 0) wq[wav][sp] = (int)__popcll(m);
            if (s == sp) prank = (int)__popcll(m & ltmask);
        }
        for (int i = tid; i < 416; i += TPB) idxl[i] = -1;
        ldsbar();   // b1: xb, wq, sentinels (and prologue wlds/clds) visible

        // ---- all-thread scan: per-species tile bases
        int tb[6];
        {
            int t = 0;
            #pragma unroll
            for (int sp = 0; sp < 5; ++sp) {
                tb[sp] = t;
                int c = wq[0][sp] + wq[1][sp] + wq[2][sp] + wq[3][sp];
                t += (c + 31) >> 5;
            }
            tb[5] = t;
        }
        // ---- rank-write local row into species segment
        if (s >= 0) {
            int off = tb[s] * 32 + prank;
            for (int w2 = 0; w2 < wav; ++w2) off += wq[w2][s];
            idxl[off] = tid;
        }

        // ---- issue NEXT window's global loads. Phase B is vmcnt-free now,
        //      so these stay in flight until next stage with zero interference.
        const int wn = w + gridDim.x;
        if (wn < nwin) {
            #pragma unroll
            for (int k = 0; k < 4; ++k) {
                long fo = (long)wn * (WIN * 32) + k * 2048 + tid * 8;
                if (fo > fmaxo) fo = fmaxo;
                pa[k] = *(const float4*)(X + fo);
                pb[k] = *(const float4*)(X + fo + 4);
            }
            const int row = wn * WIN + tid;
            svp = (row < B) ? sid[row] : -1;
        }
        ldsbar();   // b2: idxl visible

        // ---- phase B: single-species tiles; weights+frags+consts all LDS
        const int ntl = tb[5];
        for (int t = wav; t < ntl; t += 4) {
            int csp = 0;
            #pragma unroll
            for (int k = 1; k < 5; ++k) csp += (t >= tb[k]) ? 1 : 0;
            csp = __builtin_amdgcn_readfirstlane(csp);
            const int lid = idxl[t * 32 + ln];
            const int r = lid < 0 ? 0 : lid;

            const unsigned* wp = wlds + csp * 2048;    // ds_read_b128, no vmcnt
            FU w00, w01, w10, w11, w20, w21, w30, w31;
            w00.q = *(const u32x4*)(wp + (0 * 64 + l) * 4);
            w01.q = *(const u32x4*)(wp + (1 * 64 + l) * 4);
            w10.q = *(const u32x4*)(wp + (2 * 64 + l) * 4);
            w11.q = *(const u32x4*)(wp + (3 * 64 + l) * 4);
            w20.q = *(const u32x4*)(wp + (4 * 64 + l) * 4);
            w21.q = *(const u32x4*)(wp + (5 * 64 + l) * 4);
            w30.q = *(const u32x4*)(wp + (6 * 64 + l) * 4);
            w31.q = *(const u32x4*)(wp + (7 * 64 + l) * 4);

            const float* cp = clds + csp * 96;
            f32x16 a1 = *(const f32x16*)(cp + hi * 16);
            f32x16 a2 = *(const f32x16*)(cp + 32 + hi * 16);

            const int rs = r & 3;
            const bf16x8 b0 = *(const bf16x8*)(xb + r * 64 + ((hi ^ rs) << 4));
            const bf16x8 b1 = *(const bf16x8*)(xb + r * 64 + (((2 + hi) ^ rs) << 4));

            a1 = __builtin_amdgcn_mfma_f32_32x32x16_bf16(w00.v, b0, a1, 0, 0, 0);
            a2 = __builtin_amdgcn_mfma_f32_32x32x16_bf16(w10.v, b0, a2, 0, 0, 0);
            a1 = __builtin_amdgcn_mfma_f32_32x32x16_bf16(w01.v, b1, a1, 0, 0, 0);
            a2 = __builtin_amdgcn_mfma_f32_32x32x16_bf16(w11.v, b1, a2, 0, 0, 0);

            bf16x8 h0, h1;
            reluT(a1, h0, h1);
            a2 = __builtin_amdgcn_mfma_f32_32x32x16_bf16(w20.v, h0, a2, 0, 0, 0);
            a2 = __builtin_amdgcn_mfma_f32_32x32x16_bf16(w21.v, h1, a2, 0, 0, 0);

            bf16x8 g0, g1;
            reluT(a2, g0, g1);
            f32x16 a3 = *(const f32x16*)(cp + 64 + hi * 16);
            a3 = __builtin_amdgcn_mfma_f32_32x32x16_bf16(w30.v, g0, a3, 0, 0, 0);
            a3 = __builtin_amdgcn_mfma_f32_32x32x16_bf16(w31.v, g1, a3, 0, 0, 0);

            if (lid >= 0) {
                // relu + pack bf16 pairs into LDS out-stage at natural row lid
                // piece (hi,q) = features 8q+4hi+0..3 -> u32-offset
                // (4q+2hi) ^ ((lid&7)<<1)  [bijective within row]
                #pragma unroll
                for (int q = 0; q < 4; ++q) {
                    unsigned u0 = pkbf(fmaxf(a3[4 * q + 0], 0.f), fmaxf(a3[4 * q + 1], 0.f));
                    unsigned u1 = pkbf(fmaxf(a3[4 * q + 2], 0.f), fmaxf(a3[4 * q + 3], 0.f));
                    const int off = (4 * q + 2 * hi) ^ ((lid & 7) << 1);
                    u32x2 uu; uu[0] = u0; uu[1] = u1;
                    *(u32x2*)(obh + lid * 16 + off) = uu;
                }
            }
        }
        ldsbar();   // b3: obh visible

        // ---- flush: LDS out-stage -> global, fully coalesced 16B pieces
        #pragma unroll
        for (int k = 0; k < 8; ++k) {
            const int p = k * TPB + tid;
            const int row = p >> 3, sl = p & 7;
            if (row < rows) {
                const int off = (sl * 2) ^ ((row & 7) << 1);
                u32x2 uu = *(const u32x2*)(obh + row * 16 + off);
                float4 v;
                v.x = __uint_as_float(uu[0] << 16);
                v.y = __uint_as_float(uu[0] & 0xffff0000u);
                v.z = __uint_as_float(uu[1] << 16);
                v.w = __uint_as_float(uu[1] & 0xffff0000u);
                *(float4*)(out + (long)(wbase + row) * 32 + sl * 4) = v;
            }
        }
    }
}

extern "C" void kernel_launch(void* const* d_in, const int* in_sizes, int n_in,
                              void* d_out, int out_size, void* d_ws, size_t ws_size,
                              hipStream_t stream) {
    const float* X   = (const float*)d_in[0];
    const int*   sid = (const int*)d_in[1];
    const float* W1  = (const float*)d_in[2];
    const float* b1  = (const float*)d_in[3];
    const float* g1  = (const float*)d_in[4];
    const float* be1 = (const float*)d_in[5];
    const float* mu1 = (const float*)d_in[6];
    const float* va1 = (const float*)d_in[7];
    const float* W2  = (const float*)d_in[8];
    const float* b2  = (const float*)d_in[9];
    const float* g2  = (const float*)d_in[10];
    const float* be2 = (const float*)d_in[11];
    const float* mu2 = (const float*)d_in[12];
    const float* va2 = (const float*)d_in[13];
    const float* Wsc = (const float*)d_in[14];
    const float* bsc = (const float*)d_in[15];
    const float* Wsh = (const float*)d_in[16];
    const float* bsh = (const float*)d_in[17];
    float* out = (float*)d_out;
    const int B = in_sizes[1];

    const int nwin = (B + WIN - 1) / WIN;
    const int nblocks = min(NBLK, nwin);
    k_main<<<nblocks, TPB, 0, stream>>>(X, sid,
                                        W1, b1, g1, be1, mu1, va1,
                                        W2, b2, g2, be2, mu2, va2,
                                        Wsc, bsc, Wsh, bsh, out, B);
}